// Round 8
// baseline (4579.529 us; speedup 1.0000x reference)
//
#include <hip/hip_runtime.h>
#include <stdint.h>

#define B_ 64
#define T_ 512
#define D_ 1024
#define U_ 1024
#define G4_ 4096
#define M_ (B_ * T_)  // 32768

typedef unsigned short u16;
typedef float f32x4 __attribute__((ext_vector_type(4)));
typedef _Float16 f16x8 __attribute__((ext_vector_type(8)));
typedef unsigned short u16x4 __attribute__((ext_vector_type(4)));

__device__ __forceinline__ u16 f2h(float f) {
  union { _Float16 h; u16 u; } v; v.h = (_Float16)f; return v.u;
}
__device__ __forceinline__ float h2f(u16 u) {
  union { _Float16 h; u16 u; } v; v.u = u; return (float)v.h;
}
__device__ __forceinline__ float sigm(float x) { return 1.f / (1.f + __expf(-x)); }
__device__ __forceinline__ float tanhf_(float x) {
  x = fminf(12.f, fmaxf(-12.f, x));
  float e = __expf(2.f * x);
  return (e - 1.f) / (e + 1.f);
}

__device__ __forceinline__ void glds16(const void* g, void* l) {
  __builtin_amdgcn_global_load_lds(
      (const __attribute__((address_space(1))) uint32_t*)g,
      (__attribute__((address_space(3))) uint32_t*)l, 16, 0, 0);
}

// ---- row-strided stager (GEMM + fused fallback): swizzle (row&7)<<4 applied
// to GLOBAL source (rule #21), LDS linear; read_frag applies the same XOR.
template <int R>
__device__ __forceinline__ void stage_tile(const char* gbase, long gs, char* lds, int tid) {
  const int lane = tid & 63, wid = tid >> 6;
#pragma unroll
  for (int j = wid; j < R / 8; j += 4) {
    const int row = j * 8 + (lane >> 3);
    const int lg = ((lane & 7) * 16) ^ ((row & 7) << 4);
    glds16(gbase + (long)row * gs + lg, lds + j * 1024);
  }
}

__device__ __forceinline__ f16x8 read_frag(const char* lds, int row, int kbyte) {
  const int ph = row * 128 + (kbyte ^ ((row & 7) << 4));
  return *(const f16x8*)(lds + ph);
}

#define MFMA_(a, b, c) __builtin_amdgcn_mfma_f32_16x16x32_f16(a, b, c, 0, 0, 0)

// raw barrier without VMEM drain (LDS ordering only)
#define BAR_LGKM() asm volatile("s_waitcnt lgkmcnt(0)\n\ts_barrier" ::: "memory")

// ---------------- prep kernels ----------------

__global__ __launch_bounds__(256) void cast_x_kernel(const float* __restrict__ x,
                                                     u16* __restrict__ xb) {
  const long n = (long)M_ * D_ / 4;
  for (long i = (long)blockIdx.x * blockDim.x + threadIdx.x; i < n;
       i += (long)gridDim.x * blockDim.x) {
    f32x4 v = ((const f32x4*)x)[i];
    u16x4 r;
#pragma unroll
    for (int j = 0; j < 4; ++j) r[j] = f2h(v[j]);
    ((u16x4*)xb)[i] = r;
  }
}

// Packed column p = ub*64 + g*16 + ui  <->  original col = g*1024 + ub*16 + ui.
__global__ __launch_bounds__(256) void pack_w_kernel(const float* __restrict__ Wf,
                                                     const float* __restrict__ Wb,
                                                     u16* __restrict__ wxT,
                                                     u16* __restrict__ whT) {
  const int idx = blockIdx.x * 256 + threadIdx.x;
  const int p = idx & 4095;
  const int kc = (idx >> 12) & 63;
  const int part = (idx >> 18) & 1;
  const int d = (idx >> 19) & 1;
  const float* W = d ? Wb : Wf;
  const int orig = ((p >> 4) & 3) * 1024 + ((p >> 6) << 4) + (p & 15);
  u16* dst = (part ? whT : wxT) + ((long)d * G4_ + p) * 1024 + kc * 16;
  const float* src = W + ((long)(part * 1024 + kc * 16)) * G4_ + orig;
#pragma unroll
  for (int j = 0; j < 16; ++j) dst[j] = f2h(src[(long)j * G4_]);
}

// ---------------- big x-projection GEMM (128x128 tile) ----------------
// Writes xp2 layout [d][t][ub(64)][b(64)][pl(64)] fp16, bias folded in.
__global__ __launch_bounds__(256) void gemm_xproj2(const u16* __restrict__ xbf,
                                                   const u16* __restrict__ wT,
                                                   const float* __restrict__ bF,
                                                   const float* __restrict__ bB,
                                                   u16* __restrict__ xp2) {
  __shared__ __align__(16) char smem[64 * 1024];
  const int tid = threadIdx.x, lane = tid & 63, wid = tid >> 6;
  const int wr = wid >> 1, wc = wid & 1;
  const int tm = blockIdx.x * 128, tn = blockIdx.y * 128, d = blockIdx.z;
  const char* Ag = (const char*)xbf + (long)tm * 2048;
  const char* Bg = (const char*)wT + ((long)d * G4_ + tn) * 2048;

  f32x4 acc[4][4];
#pragma unroll
  for (int mi = 0; mi < 4; ++mi)
#pragma unroll
    for (int ni = 0; ni < 4; ++ni)
#pragma unroll
      for (int v = 0; v < 4; ++v) acc[mi][ni][v] = 0.f;

  stage_tile<128>(Ag, 2048, smem, tid);
  stage_tile<128>(Bg, 2048, smem + 32768, tid);
  __syncthreads();
  const int rA = lane & 15, kb = (lane >> 4) * 16;

  for (int cc = 0; cc < 16; ++cc) {
    const int cur = cc & 1;
    char* Ac = smem + cur * 16384;
    char* Bc = smem + 32768 + cur * 16384;
    if (cc + 1 < 16) {
      stage_tile<128>(Ag + (cc + 1) * 128, 2048, smem + (cur ^ 1) * 16384, tid);
      stage_tile<128>(Bg + (cc + 1) * 128, 2048, smem + 32768 + (cur ^ 1) * 16384, tid);
    }
    f16x8 aF[4][2], bFr[4][2];
#pragma unroll
    for (int mi = 0; mi < 4; ++mi)
#pragma unroll
      for (int ks = 0; ks < 2; ++ks)
        aF[mi][ks] = read_frag(Ac, wr * 64 + mi * 16 + rA, kb + ks * 64);
#pragma unroll
    for (int ni = 0; ni < 4; ++ni)
#pragma unroll
      for (int ks = 0; ks < 2; ++ks)
        bFr[ni][ks] = read_frag(Bc, wc * 64 + ni * 16 + rA, kb + ks * 64);
#pragma unroll
    for (int mi = 0; mi < 4; ++mi)
#pragma unroll
      for (int ni = 0; ni < 4; ++ni)
#pragma unroll
        for (int ks = 0; ks < 2; ++ks)
          acc[mi][ni] = MFMA_(aF[mi][ks], bFr[ni][ks], acc[mi][ni]);
    __syncthreads();
  }

  const float* bias = d ? bB : bF;
#pragma unroll
  for (int ni = 0; ni < 4; ++ni) {
    const int p = tn + wc * 64 + ni * 16 + rA;
    const int orig = ((p >> 4) & 3) * 1024 + ((p >> 6) << 4) + (p & 15);
    const float bv = bias[orig];
    const int ub2 = p >> 6, pl = p & 63;
#pragma unroll
    for (int mi = 0; mi < 4; ++mi) {
      const int m0 = tm + wr * 64 + mi * 16 + (lane >> 4) * 4;
#pragma unroll
      for (int v = 0; v < 4; ++v) {
        const int m = m0 + v, b = m >> 9, t = m & 511;
        xp2[((((long)d * T_ + t) * 64 + ub2) * 64 + b) * 64 + pl] =
            f2h(acc[mi][ni][v] + bv);
      }
    }
  }
}

// ---------------- persistent recurrent kernel v4 ----------------
// 128 blocks (d, ub), 512 threads, 8 waves = 4 M-groups x 2 K-halves.
// W LDS-resident in FRAGMENT-LINEAR layout: fragment f=(ni<<5)|kkg is 1KB at
// smem+f*1024, lane-sequential -> conflict-free ds_read_b128.
// VER=1: h versioned [T+1][d][b][u] (write-once per slot) -> A-loads normal
// cached (XCD L2 shared; no stale-alias hazard). VER=0: r7 ping-pong + LLC-
// direct A-loads. h stores always sc0/sc1 write-through; flags LLC-direct.
#define ZLD 65  // zbuf row stride (floats), breaks gate-read 8-way conflict
template <int VER>
__global__ __launch_bounds__(512) void lstm_persist(
    const u16* __restrict__ whT, const u16* __restrict__ xp2,
    u16* __restrict__ hst, float* __restrict__ out, uint32_t* flags) {
  __shared__ __align__(16) char smem[131072 + ZLD * 64 * 4];
  float* zbuf = (float*)(smem + 131072);
  const int tid = threadIdx.x, lane = tid & 63, wid = tid >> 6;
  const int bx = blockIdx.x, d = bx & 1, ub = bx >> 1;
  const int wm = wid & 3, kh = wid >> 2, rA = lane & 15, kq = lane >> 4;

  // ---- stage W once, fragment-linear: f=(ni<<5)|kkg; lane -> row ni*16+
  // (lane&15), kbytes kkg*64+(lane>>4)*16; LDS dst f*1024 (+lane*16 by HW) ----
  {
    const char* wbase = (const char*)(whT + ((long)d * G4_ + ub * 64) * 1024);
#pragma unroll
    for (int q = 0; q < 16; ++q) {
      const int f = wid * 16 + q;
      const int ni = f >> 5, kkg = f & 31;
      const int row = ni * 16 + (lane & 15);
      glds16(wbase + (long)row * 2048 + kkg * 64 + (lane >> 4) * 16,
             smem + f * 1024);
    }
  }
  asm volatile("s_waitcnt vmcnt(0)" ::: "memory");
  __syncthreads();

  // gate-phase mapping: thread -> b = tid>>3, u-pair up = tid&7
  const int b_g = tid >> 3, up_g = tid & 7;
  const int u_g = ub * 16 + up_g * 2;
  float creg0 = 0.f, creg1 = 0.f;
  uint32_t* fl = flags + (long)d * 64 * 4;  // 16B-padded slots

  for (int s = 0; s < T_; ++s) {
    const int t = d ? (T_ - 1 - s) : s;

    // ---- xp loads issued BEFORE the poll (cached; complete during spin) ----
    const u16* xb0 = xp2 + ((((long)d * T_ + t) * 64 + ub) * 64 + b_g) * 64 + up_g * 2;
    uint32_t xr[4];
#define XLOAD(g)                                                        \
  asm volatile("global_load_dword %0, %1, off offset:%2"               \
               : "=v"(xr[g]) : "v"(xb0), "n"(g * 32) : "memory")
    XLOAD(0); XLOAD(1); XLOAD(2); XLOAD(3);
#undef XLOAD

    // ---- barrier: all 64 blocks of this dir finished step s-1 ----
    if (wid == 0) {
      const uint32_t* fp = fl + lane * 4;
      int it = 0;
      while (true) {
        uint32_t v;
        asm volatile("global_load_dword %0, %1, off sc0 sc1\n\ts_waitcnt vmcnt(0)"
                     : "=v"(v) : "v"(fp) : "memory");
        if (__all(v >= (uint32_t)s)) break;
        __builtin_amdgcn_s_sleep(1);
        if (++it > (1 << 17)) break;  // bailout: terminate rather than hang
      }
    }
    BAR_LGKM();  // B1

    // ---- A-loads: 16 x dwordx4; VER1 cached (L2-shared), VER0 LLC-direct ----
    const u16* hr = hst + (VER ? (long)s * 131072 : (long)(s & 1) * 131072)
                    + (long)d * 65536;
    const char* abase =
        (const char*)(hr + ((long)(wm * 16 + rA)) * 1024) + kh * 1024 + kq * 16;
    f16x8 areg[16];
#define ALOADC(i)                                                       \
  asm volatile("global_load_dwordx4 %0, %1, off offset:%2"             \
               : "=v"(areg[i]) : "v"(abase), "n"(i * 64) : "memory")
#define ALOADU(i)                                                       \
  asm volatile("global_load_dwordx4 %0, %1, off offset:%2 sc0 sc1"     \
               : "=v"(areg[i]) : "v"(abase), "n"(i * 64) : "memory")
    if (VER) {
      ALOADC(0); ALOADC(1); ALOADC(2); ALOADC(3);
      ALOADC(4); ALOADC(5); ALOADC(6); ALOADC(7);
      ALOADC(8); ALOADC(9); ALOADC(10); ALOADC(11);
      ALOADC(12); ALOADC(13); ALOADC(14); ALOADC(15);
    } else {
      ALOADU(0); ALOADU(1); ALOADU(2); ALOADU(3);
      ALOADU(4); ALOADU(5); ALOADU(6); ALOADU(7);
      ALOADU(8); ALOADU(9); ALOADU(10); ALOADU(11);
      ALOADU(12); ALOADU(13); ALOADU(14); ALOADU(15);
    }
#undef ALOADC
#undef ALOADU
    asm volatile("s_waitcnt vmcnt(0)" ::: "memory");  // A (and earlier xp) done
    __builtin_amdgcn_sched_barrier(0);  // rule #18

    // ---- MFMA burst: conflict-free fragment-linear B reads ----
    f32x4 acc[4];
#pragma unroll
    for (int ni = 0; ni < 4; ++ni)
#pragma unroll
      for (int v = 0; v < 4; ++v) acc[ni][v] = 0.f;
    const char* bbase = smem + (kh << 14) + (lane << 4);
#pragma unroll
    for (int kk = 0; kk < 16; ++kk) {
#pragma unroll
      for (int ni = 0; ni < 4; ++ni) {
        const f16x8 bF = *(const f16x8*)(bbase + (ni << 15) + (kk << 10));
        acc[ni] = MFMA_(areg[kk], bF, acc[ni]);
      }
    }

    // ---- K-combine via zbuf: kh1 writes, kh0 adds ----
    if (kh == 1) {
#pragma unroll
      for (int ni = 0; ni < 4; ++ni)
#pragma unroll
        for (int v = 0; v < 4; ++v)
          zbuf[(wm * 16 + kq * 4 + v) * ZLD + ni * 16 + rA] = acc[ni][v];
    }
    BAR_LGKM();  // B2
    if (kh == 0) {
#pragma unroll
      for (int ni = 0; ni < 4; ++ni)
#pragma unroll
        for (int v = 0; v < 4; ++v) {
          const int ix = (wm * 16 + kq * 4 + v) * ZLD + ni * 16 + rA;
          zbuf[ix] += acc[ni][v];
        }
    }
    BAR_LGKM();  // B3

    // ---- gates: 2 adjacent units of one batch per thread ----
    const float* zb = zbuf + b_g * ZLD + up_g * 2;
    const float zi0 = zb[0]  + h2f((u16)(xr[0] & 0xffff));
    const float zi1 = zb[1]  + h2f((u16)(xr[0] >> 16));
    const float zf0 = zb[16] + h2f((u16)(xr[1] & 0xffff));
    const float zf1 = zb[17] + h2f((u16)(xr[1] >> 16));
    const float zo0 = zb[32] + h2f((u16)(xr[2] & 0xffff));
    const float zo1 = zb[33] + h2f((u16)(xr[2] >> 16));
    const float zg0 = zb[48] + h2f((u16)(xr[3] & 0xffff));
    const float zg1 = zb[49] + h2f((u16)(xr[3] >> 16));
    const float cn0 = sigm(zf0) * creg0 + sigm(zi0) * tanhf_(zg0);
    const float cn1 = sigm(zf1) * creg1 + sigm(zi1) * tanhf_(zg1);
    const float hn0 = sigm(zo0) * tanhf_(cn0);
    const float hn1 = sigm(zo1) * tanhf_(cn1);
    creg0 = cn0; creg1 = cn1;

    // ---- h store write-through -> ack -> barrier -> flag ----
    u16* hw = hst + (VER ? (long)(s + 1) * 131072 : (long)((s + 1) & 1) * 131072)
              + (long)d * 65536;
    const uint32_t hv = (uint32_t)f2h(hn0) | ((uint32_t)f2h(hn1) << 16);
    u16* hptr = hw + (long)b_g * 1024 + u_g;
    asm volatile("global_store_dword %0, %1, off sc0 sc1"
                 :: "v"(hptr), "v"(hv) : "memory");
    asm volatile("s_waitcnt vmcnt(0)" ::: "memory");
    BAR_LGKM();  // B4
    if (tid == 0) {
      const uint32_t fv = (uint32_t)(s + 1);
      uint32_t* fp2 = fl + ub * 4;
      asm volatile("global_store_dword %0, %1, off sc0 sc1"
                   :: "v"(fp2), "v"(fv) : "memory");
    }

    // ---- out store AFTER release ----
    float2 o2; o2.x = hn0; o2.y = hn1;
    *(float2*)(out + ((long)b_g * T_ + t) * 2048 + d * 1024 + u_g) = o2;
  }
}

// ---------------- fused fallback (small workspace): r3-proven structure ------
__global__ __launch_bounds__(256) void lstm_step_fused(
    const u16* __restrict__ whT, const u16* __restrict__ wxT,
    const u16* __restrict__ xbf,
    const float* __restrict__ bF, const float* __restrict__ bB,
    const u16* __restrict__ h_read, u16* __restrict__ h_write,
    float* __restrict__ c_state, float* __restrict__ out, int s) {
  __shared__ __align__(16) char smem[32 * 1024];
  float* zbuf = (float*)smem;
  const int tid = threadIdx.x, lane = tid & 63, wid = tid >> 6;
  const int wr = wid >> 1, wc = wid & 1;
  const int ub = blockIdx.x, d = blockIdx.y;
  const int t = d ? (T_ - 1 - s) : s;
  const char* hA = (const char*)(h_read + (long)d * B_ * U_);
  const char* Bh = (const char*)(whT + ((long)d * G4_ + ub * 64) * 1024);
  const char* xA = (const char*)xbf + (long)t * (D_ * 2);
  const char* Bx = (const char*)(wxT + ((long)d * G4_ + ub * 64) * 1024);

  auto stage = [&](int cc, int buf) {
    char* Ad = smem + buf * 8192;
    char* Bd = smem + 16384 + buf * 8192;
    if (cc < 16) {
      stage_tile<64>(hA + cc * 128, U_ * 2, Ad, tid);
      stage_tile<64>(Bh + cc * 128, 1024 * 2, Bd, tid);
    } else {
      const int cx = cc - 16;
      stage_tile<64>(xA + cx * 128, (long)T_ * D_ * 2, Ad, tid);
      stage_tile<64>(Bx + cx * 128, 1024 * 2, Bd, tid);
    }
  };

  f32x4 acc[2][2];
#pragma unroll
  for (int mi = 0; mi < 2; ++mi)
#pragma unroll
    for (int ni = 0; ni < 2; ++ni)
#pragma unroll
      for (int v = 0; v < 4; ++v) acc[mi][ni][v] = 0.f;

  stage(0, 0);
  __syncthreads();
  const int rA = lane & 15, kb = (lane >> 4) * 16;

  for (int cc = 0; cc < 32; ++cc) {
    const int cur = cc & 1;
    char* Ac = smem + cur * 8192;
    char* Bc = smem + 16384 + cur * 8192;
    if (cc + 1 < 32) stage(cc + 1, cur ^ 1);
    f16x8 aF[2][2], bFr[2][2];
#pragma unroll
    for (int mi = 0; mi < 2; ++mi)
#pragma unroll
      for (int ks = 0; ks < 2; ++ks)
        aF[mi][ks] = read_frag(Ac, wr * 32 + mi * 16 + rA, kb + ks * 64);
#pragma unroll
    for (int ni = 0; ni < 2; ++ni)
#pragma unroll
      for (int ks = 0; ks < 2; ++ks)
        bFr[ni][ks] = read_frag(Bc, wc * 32 + ni * 16 + rA, kb + ks * 64);
#pragma unroll
    for (int mi = 0; mi < 2; ++mi)
#pragma unroll
      for (int ni = 0; ni < 2; ++ni)
#pragma unroll
        for (int ks = 0; ks < 2; ++ks)
          acc[mi][ni] = MFMA_(aF[mi][ks], bFr[ni][ks], acc[mi][ni]);
    __syncthreads();
  }

#pragma unroll
  for (int mi = 0; mi < 2; ++mi)
#pragma unroll
    for (int ni = 0; ni < 2; ++ni)
#pragma unroll
      for (int v = 0; v < 4; ++v) {
        const int row = wr * 32 + mi * 16 + (lane >> 4) * 4 + v;
        const int col = wc * 32 + ni * 16 + rA;
        zbuf[row * 64 + col] = acc[mi][ni][v];
      }
  __syncthreads();

  const int b = tid >> 2, u0 = (tid & 3) * 4;
  const float* bias = d ? bB : bF;
#pragma unroll
  for (int j = 0; j < 4; ++j) {
    const int ui = u0 + j, u = ub * 16 + ui;
    float zi = zbuf[b * 64 + ui] + bias[u];
    float zf = zbuf[b * 64 + 16 + ui] + bias[1024 + u];
    float zo = zbuf[b * 64 + 32 + ui] + bias[2048 + u];
    float zg = zbuf[b * 64 + 48 + ui] + bias[3072 + u];
    const long ci = (((long)d * B_ + b) << 10) + u;
    const float c = c_state[ci];
    const float i_ = sigm(zi), ff = sigm(zf), o_ = sigm(zo), g_ = tanhf_(zg);
    const float cn = ff * c + i_ * g_;
    const float hn = o_ * tanhf_(cn);
    c_state[ci] = cn;
    h_write[ci] = f2h(hn);
    out[(((long)b * T_ + t) << 11) + ((long)d << 10) + u] = hn;
  }
}

// ---------------- host launch ----------------

extern "C" void kernel_launch(void* const* d_in, const int* in_sizes, int n_in,
                              void* d_out, int out_size, void* d_ws, size_t ws_size,
                              hipStream_t stream) {
  const float* x = (const float*)d_in[0];
  const float* Wf = (const float*)d_in[1];
  const float* bfp = (const float*)d_in[2];
  const float* Wb = (const float*)d_in[3];
  const float* bbp = (const float*)d_in[4];
  float* out = (float*)d_out;
  char* ws = (char*)d_ws;

  size_t off = 0;
  auto alloc = [&](size_t bytes) {
    char* p = ws + off;
    off = (off + bytes + 255) & ~(size_t)255;
    return p;
  };
  const size_t hst_ver_bytes = (size_t)(T_ + 1) * 2 * B_ * U_ * 2;  // 134.5 MB
  const size_t hst_pp_bytes = (size_t)2 * 2 * B_ * U_ * 2;          // 0.5 MB
  const size_t xproj_bytes = (size_t)2 * B_ * T_ * G4_ * 2;         // 512 MB
  const size_t fixed = (size_t)M_ * D_ * 2 + 2 * ((size_t)2 * G4_ * 1024 * 2) +
                       (size_t)2 * B_ * U_ * 4 + (size_t)2 * 64 * 16 * 4 + 4096;
  const bool versioned = ws_size >= fixed + hst_ver_bytes + xproj_bytes + 4096;
  const bool fusedp = ws_size < fixed + hst_pp_bytes + xproj_bytes + 4096;

  u16* xbf = (u16*)alloc((size_t)M_ * D_ * 2);            // 64 MB
  u16* wxT = (u16*)alloc((size_t)2 * G4_ * 1024 * 2);     // 16 MB
  u16* whT = (u16*)alloc((size_t)2 * G4_ * 1024 * 2);     // 16 MB
  u16* hst = (u16*)alloc(versioned ? hst_ver_bytes : hst_pp_bytes);
  float* cst = (float*)alloc((size_t)2 * B_ * U_ * 4);    // cell state (fallback)
  uint32_t* flags = (uint32_t*)alloc((size_t)2 * 64 * 16 * 4);
  u16* xproj = fusedp ? nullptr : (u16*)alloc(xproj_bytes);

  // zero h slot(s) used as step-0 input + flags
  hipMemsetAsync(hst, 0, versioned ? (size_t)2 * B_ * U_ * 2 : hst_pp_bytes, stream);
  hipMemsetAsync(flags, 0, (size_t)2 * 64 * 16 * 4, stream);

  cast_x_kernel<<<2048, 256, 0, stream>>>(x, xbf);
  pack_w_kernel<<<4096, 256, 0, stream>>>(Wf, Wb, wxT, whT);

  if (!fusedp) {
    dim3 gg(M_ / 128, G4_ / 128, 2);
    gemm_xproj2<<<gg, 256, 0, stream>>>(xbf, wxT, bfp, bbp, xproj);
    if (versioned)
      lstm_persist<1><<<128, 512, 0, stream>>>(whT, xproj, hst, out, flags);
    else
      lstm_persist<0><<<128, 512, 0, stream>>>(whT, xproj, hst, out, flags);
  } else {
    hipMemsetAsync(cst, 0, (size_t)2 * B_ * U_ * 4, stream);
    for (int s = 0; s < T_; ++s) {
      const u16* hr = hst + (size_t)(s & 1) * 2 * B_ * U_;
      u16* hw = hst + (size_t)((s + 1) & 1) * 2 * B_ * U_;
      lstm_step_fused<<<dim3(64, 2), 256, 0, stream>>>(whT, wxT, xbf, bfp, bbp,
                                                       hr, hw, cst, out, s);
    }
  }
}